// Round 10
// baseline (41.389 us; speedup 1.0000x reference)
//
#include <hip/hip_runtime.h>

#define DI __device__ __forceinline__

constexpr int BATCH = 256;
constexpr int INF   = 4096;   // in_features
constexpr int NGRP  = 1024;   // INF/4
constexpr int MOUT  = 4096;   // out_features

using bf16x8 = __attribute__((ext_vector_type(8))) short;
using f32x4  = __attribute__((ext_vector_type(4))) float;

// D4 half-codebook, stored as 2x the actual values (int8); actual = v * 0.5
__device__ __constant__ signed char D4_I8[512] = {
     0, 0, 0, 0,  -4, 0, 0, 0,  -2,-2,-2,-2,  -2,-2,-2, 0,  -2,-2,-2, 2,  -2,-2, 0,-2,  -2,-2, 0, 0,  -2,-2, 0, 2,
    -2,-2, 2,-2,  -2,-2, 2, 0,  -2,-2, 2, 2,  -2, 0,-2,-2,  -2, 0,-2, 0,  -2, 0,-2, 2,  -2, 0, 0,-2,  -2, 0, 0, 0,
    -2, 0, 0, 2,  -2, 0, 2,-2,  -2, 0, 2, 0,  -2, 0, 2, 2,  -2, 2,-2,-2,  -2, 2,-2, 0,  -2, 2,-2, 2,  -2, 2, 0,-2,
    -2, 2, 0, 0,  -2, 2, 0, 2,  -2, 2, 2,-2,  -2, 2, 2, 0,  -2, 2, 2, 2,   0,-4, 0, 0,   0,-2,-2,-2,   0,-2,-2, 0,
     0,-2,-2, 2,   0,-2, 0,-2,   0,-2, 0, 0,   0,-2, 0, 2,   0,-2, 2,-2,   0,-2, 2, 0,   0,-2, 2, 2,   0, 0,-4, 0,
     0, 0,-2,-2,   0, 0,-2, 0,   0, 0,-2, 2,   0, 0, 0,-4,   0, 0, 0,-2,
    -3,-1,-3,-1,  -3,-1,-3, 1,  -3,-1,-1,-3,  -3,-1,-1,-1,  -3,-1,-1, 1,  -3,-1,-1, 3,  -3,-1, 1,-3,  -3,-1, 1,-1,
    -3,-1, 1, 1,  -3,-1, 1, 3,  -3,-1, 3,-1,  -3,-1, 3, 1,  -3, 1,-3,-1,  -3, 1,-3, 1,  -3, 1,-1,-3,  -3, 1,-1,-1,
    -3, 1,-1, 1,  -3, 1,-1, 3,  -3, 1, 1,-3,  -3, 1, 1,-1,  -3, 1, 1, 1,  -3, 1, 1, 3,  -3, 1, 3,-1,  -3, 1, 3, 1,
    -3, 3,-1,-1,  -3, 3, 1,-1,  -3, 3, 1, 1,  -1,-3,-3,-1,  -1,-3,-3, 1,  -1,-3,-1,-3,  -1,-3,-1,-1,  -1,-3,-1, 1,
    -1,-3,-1, 3,  -1,-3, 1,-3,  -1,-3, 1,-1,  -1,-3, 1, 1,  -1,-3, 1, 3,  -1,-3, 3,-1,  -1,-3, 3, 1,  -1,-1,-3,-3,
    -1,-1,-3,-1,  -1,-1,-3, 1,  -1,-1,-3, 3,  -1,-1,-1,-3,  -1,-1,-1,-1,  -1,-1,-1, 1,  -1,-1,-1, 3,  -1,-1, 1,-3,
    -1,-1, 1,-1,  -1,-1, 1, 1,  -1,-1, 1, 3,  -1,-1, 3,-3,  -1,-1, 3,-1,  -1,-1, 3, 1,  -1,-1, 3, 3,  -1, 1,-3,-3,
    -1, 1,-3,-1,  -1, 1,-3, 1,  -1, 1,-3, 3,  -1, 1,-1,-3,  -1, 1,-1,-1,  -1, 1,-1, 1,  -1, 1,-1, 3,  -1, 1, 1,-3,
    -1, 1, 1,-1,  -1, 1, 1, 1,  -1, 1, 1, 3,  -1, 1, 3,-3,  -1, 1, 3,-1,  -1, 1, 3, 1,  -1, 1, 3, 3,  -1, 3,-3,-1,
    -1, 3,-3, 1,  -1, 3,-1,-3,  -1, 3,-1,-1,  -1, 3,-1, 1,  -1, 3,-1, 3,  -1, 3, 1,-3,  -1, 3, 1,-1,  -1, 3, 1, 1,
    -1, 3, 1, 3,  -1, 3, 3,-1,  -1, 3, 3, 1
};

DI unsigned short f2bf(float f) {  // f32 -> bf16 bits, round-to-nearest-even
  unsigned int u = __float_as_uint(f);
  u += 0x7fffu + ((u >> 16) & 1u);
  return (unsigned short)(u >> 16);
}

// Build Xa = scaled input in fragment-linear layout Xa[k>>5][m][(k>>3)&3][8]
__global__ __launch_bounds__(256) void prep_kernel(
    const float* __restrict__ inp, const float* __restrict__ sw,
    const float* __restrict__ qs, unsigned short* __restrict__ xa) {
  int i  = blockIdx.x * 256 + threadIdx.x;  // 16B slot id, 131072 total
  int j  = i & 3;                           // k-oct within 32-block
  int m  = (i >> 2) & 255;
  int kb = i >> 10;                         // k >> 5
  const float* ip = inp + (size_t)m * INF + kb * 32 + j * 8;
  float4 f0 = *reinterpret_cast<const float4*>(ip);
  float4 f1 = *reinterpret_cast<const float4*>(ip + 4);
  const float* sp = sw + kb * 32 + j * 8;
  float4 s0 = *reinterpret_cast<const float4*>(sp);
  float4 s1 = *reinterpret_cast<const float4*>(sp + 4);
  int g = kb * 8 + j * 2;
  float q0 = qs[g], q1 = qs[g + 1];
  union { unsigned short u[8]; uint4 v; } o;
  o.u[0] = f2bf(f0.x * s0.x * q0); o.u[1] = f2bf(f0.y * s0.y * q0);
  o.u[2] = f2bf(f0.z * s0.z * q0); o.u[3] = f2bf(f0.w * s0.w * q0);
  o.u[4] = f2bf(f1.x * s1.x * q1); o.u[5] = f2bf(f1.y * s1.y * q1);
  o.u[6] = f2bf(f1.z * s1.z * q1); o.u[7] = f2bf(f1.w * s1.w * q1);
  reinterpret_cast<uint4*>(xa)[i] = o.v;
}

// ---------------- single fused dequant-GEMM (no partials, no repack) -------
// Grid 256 = 2 m-tiles x 128 n-strips (pairs bid/bid+128 share n -> same XCD
// so the 128 KB Qidxs strip is fetched from HBM once, L2-hit by the partner).
// Block 512 thr / 8 waves = 2 m-halves x 4 k-quarters; K=4096 split in-block,
// partial planes reduced via LDS, output written once. Hot loop: 32 fully
// hand-unrolled steps on NAMED registers only (q 2-ahead, b-lookup 1-ahead).

#define MM(A, B, C) C = __builtin_amdgcn_mfma_f32_16x16x32_bf16(A, B, C, 0, 0, 0)
#define LD8(p) (*reinterpret_cast<const bf16x8*>(p))

#define QL(QB, T) do { \
    QB##x = *reinterpret_cast<const int2*>(qb0 + (T) * 8); \
    QB##y = *reinterpret_cast<const int2*>(qb1 + (T) * 8); } while (0)

#define BLOOK(BB, QB) do { \
    union { unsigned long long u[2]; bf16x8 v; } c_; \
    c_.u[0] = tbl[QB##x.x & 255]; c_.u[1] = tbl[QB##x.y & 255]; BB##_0 = c_.v; \
    c_.u[0] = tbl[QB##y.x & 255]; c_.u[1] = tbl[QB##y.y & 255]; BB##_1 = c_.v; \
  } while (0)

#define AL(T) do { \
    a_0 = LD8(axb + (size_t)(T) * 16384 +    0); \
    a_1 = LD8(axb + (size_t)(T) * 16384 + 1024); \
    a_2 = LD8(axb + (size_t)(T) * 16384 + 2048); \
    a_3 = LD8(axb + (size_t)(T) * 16384 + 3072); } while (0)

#define MFMA8(BB) do { \
    MM(a_0, BB##_0, c00); MM(a_0, BB##_1, c01); \
    MM(a_1, BB##_0, c10); MM(a_1, BB##_1, c11); \
    MM(a_2, BB##_0, c20); MM(a_2, BB##_1, c21); \
    MM(a_3, BB##_0, c30); MM(a_3, BB##_1, c31); } while (0)

#define STEP_E(T) do { \
    if ((T) + 2 < 32) QL(qE, (T) + 2); \
    if ((T) + 1 < 32) BLOOK(bO, qO); \
    MFMA8(bE); \
    if ((T) + 1 < 32) AL((T) + 1); } while (0)

#define STEP_O(T) do { \
    if ((T) + 2 < 32) QL(qO, (T) + 2); \
    if ((T) + 1 < 32) BLOOK(bE, qE); \
    MFMA8(bO); \
    if ((T) + 1 < 32) AL((T) + 1); } while (0)

__global__ __launch_bounds__(512, 4) void gemm_kernel(
    const unsigned short* __restrict__ xa, const int* __restrict__ qidx,
    float* __restrict__ out) {
  __shared__ unsigned long long tbl[256];    // 2 KB sign-folded bf16x4 codebook
  __shared__ float red[6][64 * 36];          // 54 KB partial planes (pad 36)

  const int tid  = threadIdx.x;              // 0..511
  const int lane = tid & 63;
  const int wave = tid >> 6;                 // 0..7
  const int mh   = wave >> 2;                // m half (64 rows)
  const int kq   = wave & 3;                 // k quarter (1024 k)
  const int l15  = lane & 15, l4 = lane >> 4;

  const int bid = blockIdx.x;                // 0..255
  const int mt  = bid >> 7;                  // 0/1 (bid & bid+128: same XCD)
  const int ns  = bid & 127;                 // n-strip
  const int n0  = ns * 32;
  const int m0  = mt * 128 + mh * 64;

  // ---- per-lane bases (issue global loads before the tbl barrier)
  const char* axb = reinterpret_cast<const char*>(xa) +
      (size_t)(kq * 32) * 16384 + (size_t)(m0 + l15) * 64 + l4 * 16;
  const int* qb0 = qidx + (size_t)(n0 + l15) * NGRP + kq * 256 + l4 * 2;
  const int* qb1 = qb0 + 16 * NGRP;

  int2   qEx, qEy, qOx, qOy;
  bf16x8 a_0, a_1, a_2, a_3;
  bf16x8 bE_0, bE_1, bO_0, bO_1;
  f32x4  c00 = {}, c01 = {}, c10 = {}, c11 = {};
  f32x4  c20 = {}, c21 = {}, c30 = {}, c31 = {};

  QL(qE, 0);
  QL(qO, 1);
  AL(0);

  // ---- signed codebook table: tbl[i] = 4 packed bf16, tbl[i+128] = -tbl[i]
  if (tid < 256) {
    int r = tid & 127, sg = tid >> 7;
    unsigned long long v = 0;
#pragma unroll
    for (int j = 0; j < 4; ++j) {
      float f = (float)D4_I8[r * 4 + j] * 0.5f;
      unsigned int b = __float_as_uint(f) ^ (sg ? 0x80000000u : 0u);
      v |= (unsigned long long)(b >> 16) << (16 * j);
    }
    tbl[tid] = v;
  }
  __syncthreads();
  BLOOK(bE, qE);

  // ---- 32 k-steps, fully hand-unrolled, named registers only
  STEP_E(0);  STEP_O(1);  STEP_E(2);  STEP_O(3);
  STEP_E(4);  STEP_O(5);  STEP_E(6);  STEP_O(7);
  STEP_E(8);  STEP_O(9);  STEP_E(10); STEP_O(11);
  STEP_E(12); STEP_O(13); STEP_E(14); STEP_O(15);
  STEP_E(16); STEP_O(17); STEP_E(18); STEP_O(19);
  STEP_E(20); STEP_O(21); STEP_E(22); STEP_O(23);
  STEP_E(24); STEP_O(25); STEP_E(26); STEP_O(27);
  STEP_E(28); STEP_O(29); STEP_E(30); STEP_O(31);

  // ---- in-block k-reduction through LDS (kq 1..3 -> planes, kq 0 adds)
#define PWR(C, MI, NI) do { \
    pl[((MI) * 16 + l4 * 4 + 0) * 36 + (NI) * 16 + l15] = C[0]; \
    pl[((MI) * 16 + l4 * 4 + 1) * 36 + (NI) * 16 + l15] = C[1]; \
    pl[((MI) * 16 + l4 * 4 + 2) * 36 + (NI) * 16 + l15] = C[2]; \
    pl[((MI) * 16 + l4 * 4 + 3) * 36 + (NI) * 16 + l15] = C[3]; } while (0)
#define PRD(C, MI, NI) do { \
    C[0] += pl[((MI) * 16 + l4 * 4 + 0) * 36 + (NI) * 16 + l15]; \
    C[1] += pl[((MI) * 16 + l4 * 4 + 1) * 36 + (NI) * 16 + l15]; \
    C[2] += pl[((MI) * 16 + l4 * 4 + 2) * 36 + (NI) * 16 + l15]; \
    C[3] += pl[((MI) * 16 + l4 * 4 + 3) * 36 + (NI) * 16 + l15]; } while (0)

  if (kq) {
    float* pl = &red[mh * 3 + kq - 1][0];
    PWR(c00, 0, 0); PWR(c01, 0, 1); PWR(c10, 1, 0); PWR(c11, 1, 1);
    PWR(c20, 2, 0); PWR(c21, 2, 1); PWR(c30, 3, 0); PWR(c31, 3, 1);
  }
  __syncthreads();
  if (kq == 0) {
#pragma unroll
    for (int p = 0; p < 3; ++p) {
      const float* pl = &red[mh * 3 + p][0];
      PRD(c00, 0, 0); PRD(c01, 0, 1); PRD(c10, 1, 0); PRD(c11, 1, 1);
      PRD(c20, 2, 0); PRD(c21, 2, 1); PRD(c30, 3, 0); PRD(c31, 3, 1);
    }
    float* ob = out + (size_t)(m0 + l4 * 4) * MOUT + n0 + l15;
#define STO(C, MI, NI) do { \
    ob[(size_t)((MI) * 16 + 0) * MOUT + (NI) * 16] = C[0]; \
    ob[(size_t)((MI) * 16 + 1) * MOUT + (NI) * 16] = C[1]; \
    ob[(size_t)((MI) * 16 + 2) * MOUT + (NI) * 16] = C[2]; \
    ob[(size_t)((MI) * 16 + 3) * MOUT + (NI) * 16] = C[3]; } while (0)
    STO(c00, 0, 0); STO(c01, 0, 1); STO(c10, 1, 0); STO(c11, 1, 1);
    STO(c20, 2, 0); STO(c21, 2, 1); STO(c30, 3, 0); STO(c31, 3, 1);
#undef STO
  }
}

extern "C" void kernel_launch(void* const* d_in, const int* in_sizes, int n_in,
                              void* d_out, int out_size, void* d_ws, size_t ws_size,
                              hipStream_t stream) {
  const float* inp = (const float*)d_in[0];
  const float* sw  = (const float*)d_in[1];
  const float* qs  = (const float*)d_in[2];
  const int*   qi  = (const int*)d_in[3];
  float* out = (float*)d_out;
  unsigned short* xa = (unsigned short*)d_ws;   // 2 MB scratch

  prep_kernel<<<512, 256, 0, stream>>>(inp, sw, qs, xa);
  gemm_kernel<<<256, 512, 0, stream>>>(xa, qi, out);
}

// Round 11
// 34.054 us; speedup vs baseline: 1.2154x; 1.2154x over previous
//
#include <hip/hip_runtime.h>

#define DI __device__ __forceinline__

constexpr int BATCH = 256;
constexpr int INF   = 4096;   // in_features
constexpr int NGRP  = 1024;   // INF/4
constexpr int MOUT  = 4096;   // out_features

using bf16x8 = __attribute__((ext_vector_type(8))) short;
using f32x4  = __attribute__((ext_vector_type(4))) float;

// D4 half-codebook, stored as 2x the actual values (int8); actual = v * 0.5
__device__ __constant__ signed char D4_I8[512] = {
     0, 0, 0, 0,  -4, 0, 0, 0,  -2,-2,-2,-2,  -2,-2,-2, 0,  -2,-2,-2, 2,  -2,-2, 0,-2,  -2,-2, 0, 0,  -2,-2, 0, 2,
    -2,-2, 2,-2,  -2,-2, 2, 0,  -2,-2, 2, 2,  -2, 0,-2,-2,  -2, 0,-2, 0,  -2, 0,-2, 2,  -2, 0, 0,-2,  -2, 0, 0, 0,
    -2, 0, 0, 2,  -2, 0, 2,-2,  -2, 0, 2, 0,  -2, 0, 2, 2,  -2, 2,-2,-2,  -2, 2,-2, 0,  -2, 2,-2, 2,  -2, 2, 0,-2,
    -2, 2, 0, 0,  -2, 2, 0, 2,  -2, 2, 2,-2,  -2, 2, 2, 0,  -2, 2, 2, 2,   0,-4, 0, 0,   0,-2,-2,-2,   0,-2,-2, 0,
     0,-2,-2, 2,   0,-2, 0,-2,   0,-2, 0, 0,   0,-2, 0, 2,   0,-2, 2,-2,   0,-2, 2, 0,   0,-2, 2, 2,   0, 0,-4, 0,
     0, 0,-2,-2,   0, 0,-2, 0,   0, 0,-2, 2,   0, 0, 0,-4,   0, 0, 0,-2,
    -3,-1,-3,-1,  -3,-1,-3, 1,  -3,-1,-1,-3,  -3,-1,-1,-1,  -3,-1,-1, 1,  -3,-1,-1, 3,  -3,-1, 1,-3,  -3,-1, 1,-1,
    -3,-1, 1, 1,  -3,-1, 1, 3,  -3,-1, 3,-1,  -3,-1, 3, 1,  -3, 1,-3,-1,  -3, 1,-3, 1,  -3, 1,-1,-3,  -3, 1,-1,-1,
    -3, 1,-1, 1,  -3, 1,-1, 3,  -3, 1, 1,-3,  -3, 1, 1,-1,  -3, 1, 1, 1,  -3, 1, 1, 3,  -3, 1, 3,-1,  -3, 1, 3, 1,
    -3, 3,-1,-1,  -3, 3, 1,-1,  -3, 3, 1, 1,  -1,-3,-3,-1,  -1,-3,-3, 1,  -1,-3,-1,-3,  -1,-3,-1,-1,  -1,-3,-1, 1,
    -1,-3,-1, 3,  -1,-3, 1,-3,  -1,-3, 1,-1,  -1,-3, 1, 1,  -1,-3, 1, 3,  -1,-3, 3,-1,  -1,-3, 3, 1,  -1,-1,-3,-3,
    -1,-1,-3,-1,  -1,-1,-3, 1,  -1,-1,-3, 3,  -1,-1,-1,-3,  -1,-1,-1,-1,  -1,-1,-1, 1,  -1,-1,-1, 3,  -1,-1, 1,-3,
    -1,-1, 1,-1,  -1,-1, 1, 1,  -1,-1, 1, 3,  -1,-1, 3,-3,  -1,-1, 3,-1,  -1,-1, 3, 1,  -1,-1, 3, 3,  -1, 1,-3,-3,
    -1, 1,-3,-1,  -1, 1,-3, 1,  -1, 1,-3, 3,  -1, 1,-1,-3,  -1, 1,-1,-1,  -1, 1,-1, 1,  -1, 1,-1, 3,  -1, 1, 1,-3,
    -1, 1, 1,-1,  -1, 1, 1, 1,  -1, 1, 1, 3,  -1, 1, 3,-3,  -1, 1, 3,-1,  -1, 1, 3, 1,  -1, 1, 3, 3,  -1, 3,-3,-1,
    -1, 3,-3, 1,  -1, 3,-1,-3,  -1, 3,-1,-1,  -1, 3,-1, 1,  -1, 3,-1, 3,  -1, 3, 1,-3,  -1, 3, 1,-1,  -1, 3, 1, 1,
    -1, 3, 1, 3,  -1, 3, 3,-1,  -1, 3, 3, 1
};

DI unsigned short f2bf(float f) {  // f32 -> bf16 bits, round-to-nearest-even
  unsigned int u = __float_as_uint(f);
  u += 0x7fffu + ((u >> 16) & 1u);
  return (unsigned short)(u >> 16);
}

// Build Xa = scaled input in fragment-linear layout Xa[k>>5][m][(k>>3)&3][8]
__global__ __launch_bounds__(256) void prep_kernel(
    const float* __restrict__ inp, const float* __restrict__ sw,
    const float* __restrict__ qs, unsigned short* __restrict__ xa) {
  int i  = blockIdx.x * 256 + threadIdx.x;  // 16B slot id, 131072 total
  int j  = i & 3;                           // k-oct within 32-block
  int m  = (i >> 2) & 255;
  int kb = i >> 10;                         // k >> 5
  const float* ip = inp + (size_t)m * INF + kb * 32 + j * 8;
  float4 f0 = *reinterpret_cast<const float4*>(ip);
  float4 f1 = *reinterpret_cast<const float4*>(ip + 4);
  const float* sp = sw + kb * 32 + j * 8;
  float4 s0 = *reinterpret_cast<const float4*>(sp);
  float4 s1 = *reinterpret_cast<const float4*>(sp + 4);
  int g = kb * 8 + j * 2;
  float q0 = qs[g], q1 = qs[g + 1];
  union { unsigned short u[8]; uint4 v; } o;
  o.u[0] = f2bf(f0.x * s0.x * q0); o.u[1] = f2bf(f0.y * s0.y * q0);
  o.u[2] = f2bf(f0.z * s0.z * q0); o.u[3] = f2bf(f0.w * s0.w * q0);
  o.u[4] = f2bf(f1.x * s1.x * q1); o.u[5] = f2bf(f1.y * s1.y * q1);
  o.u[6] = f2bf(f1.z * s1.z * q1); o.u[7] = f2bf(f1.w * s1.w * q1);
  reinterpret_cast<uint4*>(xa)[i] = o.v;
}

// Repack v2: pure row-wise byte pack, Q2 u32[n*256 + g2] = bytes of groups
// (4*g2 .. 4*g2+3). Coalesced read+write, no transpose, no LDS.
__global__ __launch_bounds__(256) void repack_kernel(
    const int* __restrict__ qidx, unsigned* __restrict__ q2) {
  size_t i = (size_t)blockIdx.x * 256 + threadIdx.x;   // 1,048,576 total
  int4 v = reinterpret_cast<const int4*>(qidx)[i];
  q2[i] = (unsigned)(v.x & 255) | ((unsigned)(v.y & 255) << 8) |
          ((unsigned)(v.z & 255) << 16) | ((unsigned)(v.w & 255) << 24);
}

// ---------------- fused dequant-GEMM, full-K in-block ----------------------
// Grid 512 = 4 m-tiles x 128 n-strips (strip-partners on one XCD -> Q2 L2
// dedup). Block 512 thr / 8 waves = 2 mh(32 rows) x 4 kq(1024 k). W tiles
// (32n x 64k, XOR-swizzled) dequantized once per block into LDS from 16
// preloaded u32 index regs; double-buffered, ONE barrier per step. A is
// register-direct from fragment-linear Xa, one step ahead. kq partials
// reduced through LDS (aliasing the dead W buffers), output stored once.

#define MM(A, B, C) C = __builtin_amdgcn_mfma_f32_16x16x32_bf16(A, B, C, 0, 0, 0)
#define LD8(p) (*reinterpret_cast<const bf16x8*>(p))

#define STG(QV, BUFOFF) do { \
    ulonglong2 w0, w1; \
    w0.x = tbl[(QV) & 255];         w0.y = tbl[((QV) >> 8) & 255]; \
    w1.x = tbl[((QV) >> 16) & 255]; w1.y = tbl[(QV) >> 24]; \
    *reinterpret_cast<ulonglong2*>(wsm + (BUFOFF) + ws0) = w0; \
    *reinterpret_cast<ulonglong2*>(wsm + (BUFOFF) + ws1) = w1; } while (0)

#define AL(BK, T) do { \
    A##BK##_0 = LD8(axq + (size_t)(T) * 32768 +     0); \
    A##BK##_1 = LD8(axq + (size_t)(T) * 32768 +  1024); \
    A##BK##_2 = LD8(axq + (size_t)(T) * 32768 + 16384); \
    A##BK##_3 = LD8(axq + (size_t)(T) * 32768 + 17408); } while (0)

#define CMP(BK, BUFOFF) do { \
    bf16x8 b00 = LD8(wsm + (BUFOFF) + rb00); \
    bf16x8 b01 = LD8(wsm + (BUFOFF) + rb01); \
    bf16x8 b10 = LD8(wsm + (BUFOFF) + rb10); \
    bf16x8 b11 = LD8(wsm + (BUFOFF) + rb11); \
    MM(A##BK##_0, b00, c00); MM(A##BK##_0, b01, c01); \
    MM(A##BK##_1, b00, c10); MM(A##BK##_1, b01, c11); \
    MM(A##BK##_2, b10, c00); MM(A##BK##_2, b11, c01); \
    MM(A##BK##_3, b10, c10); MM(A##BK##_3, b11, c11); } while (0)

#define STEP(T, QN, CUR, NXT) do { \
    if ((T) + 1 < 16) { STG(QN, (NXT) * 4096); AL(NXT, (T) + 1); } \
    CMP(CUR, (CUR) * 4096); \
    __syncthreads(); } while (0)

__global__ __launch_bounds__(512, 4) void gemm_kernel(
    const unsigned short* __restrict__ xa, const unsigned* __restrict__ q2,
    float* __restrict__ out) {
  __shared__ unsigned long long tbl[256];   // 2 KB sign-folded bf16x4 codebook
  __shared__ ulonglong2 wt[2048];           // 32 KB: 4 kq x 2 buf x 4 KB tiles
  char* wsm  = reinterpret_cast<char*>(wt);
  float* red = reinterpret_cast<float*>(wt);   // epilogue alias (27.6 KB used)

  const int tid  = threadIdx.x;             // 0..511
  const int lane = tid & 63;
  const int wave = tid >> 6;                // 0..7
  const int kq   = wave & 3;                // k-quarter (1024 k)
  const int mh   = wave >> 2;               // m-half (32 rows)
  const int l15  = lane & 15, l4 = lane >> 4;

  const int bid = blockIdx.x;               // 0..511
  const int ns  = bid & 127;                // n-strip; partners share XCD
  const int mt  = bid >> 7;                 // 0..3
  const int n0  = ns * 32;
  const int m0  = mt * 64 + mh * 32;

  // ---- staging slot: thread -> (tile kqs, row qn, oct-quad oct2)
  const int kqs  = tid >> 7;                // which kq tile this thread stages
  const int qn   = (tid & 127) >> 2;        // 0..31
  const int oct2 = tid & 3;                 // 0..3 (4 groups each)
  const unsigned swzW = (unsigned)(qn & 7) << 4;
  const unsigned ws0 = (unsigned)(kqs * 8192) + (((unsigned)(qn * 128 + oct2 * 32)) ^ swzW);
  const unsigned ws1 = (unsigned)(kqs * 8192) + (((unsigned)(qn * 128 + oct2 * 32 + 16)) ^ swzW);

  // ---- preload all 16 steps' packed indices (issued first, L2/XCD-shared)
  const unsigned* qb = q2 + (size_t)(n0 + qn) * 256 + kqs * 64 + oct2;
  const unsigned Q0 = qb[0],  Q1 = qb[4],  Q2 = qb[8],  Q3 = qb[12];
  const unsigned Q4 = qb[16], Q5 = qb[20], Q6 = qb[24], Q7 = qb[28];
  const unsigned Q8 = qb[32], Q9 = qb[36], Qa = qb[40], Qb = qb[44];
  const unsigned Qc = qb[48], Qd = qb[52], Qe = qb[56], Qf = qb[60];

  // ---- signed codebook table: tbl[i] = 4 packed bf16, tbl[i+128] = -tbl[i]
  if (tid < 256) {
    int r = tid & 127, sg = tid >> 7;
    unsigned long long v = 0;
#pragma unroll
    for (int j = 0; j < 4; ++j) {
      float f = (float)D4_I8[r * 4 + j] * 0.5f;
      unsigned int b = __float_as_uint(f) ^ (sg ? 0x80000000u : 0u);
      v |= (unsigned long long)(b >> 16) << (16 * j);
    }
    tbl[tid] = v;
  }

  // ---- compute-side bases
  const char* axq = reinterpret_cast<const char*>(xa) +
      (size_t)kq * 524288 + (size_t)(m0 + l15) * 64 + l4 * 16;
  const unsigned swzB = (unsigned)(l15 & 7) << 4;
  const unsigned kqb  = (unsigned)(kq * 8192);
  const unsigned rb00 = kqb + (((unsigned)(l15 * 128 + l4 * 16)) ^ swzB);
  const unsigned rb01 = kqb + (((unsigned)((16 + l15) * 128 + l4 * 16)) ^ swzB);
  const unsigned rb10 = kqb + (((unsigned)(l15 * 128 + 64 + l4 * 16)) ^ swzB);
  const unsigned rb11 = kqb + (((unsigned)((16 + l15) * 128 + 64 + l4 * 16)) ^ swzB);

  bf16x8 A0_0, A0_1, A0_2, A0_3, A1_0, A1_1, A1_2, A1_3;
  f32x4  c00 = {}, c01 = {}, c10 = {}, c11 = {};

  __syncthreads();            // tbl ready
  STG(Q0, 0);                 // stage step 0 into buf 0
  AL(0, 0);                   // A bank 0 for step 0
  __syncthreads();            // buf 0 ready

  // ---- 16 k-steps (64k each), one barrier per step, dbuf LDS
  STEP(0,  Q1, 0, 1); STEP(1,  Q2, 1, 0); STEP(2,  Q3, 0, 1); STEP(3,  Q4, 1, 0);
  STEP(4,  Q5, 0, 1); STEP(5,  Q6, 1, 0); STEP(6,  Q7, 0, 1); STEP(7,  Q8, 1, 0);
  STEP(8,  Q9, 0, 1); STEP(9,  Qa, 1, 0); STEP(10, Qb, 0, 1); STEP(11, Qc, 1, 0);
  STEP(12, Qd, 0, 1); STEP(13, Qe, 1, 0); STEP(14, Qf, 0, 1); STEP(15, Q0, 1, 0);

  // ---- kq-reduction through LDS (aliases dead W buffers), store once
#define PWR(C, MI, NI) do { \
    pl[((MI) * 16 + l4 * 4 + 0) * 36 + (NI) * 16 + l15] = C[0]; \
    pl[((MI) * 16 + l4 * 4 + 1) * 36 + (NI) * 16 + l15] = C[1]; \
    pl[((MI) * 16 + l4 * 4 + 2) * 36 + (NI) * 16 + l15] = C[2]; \
    pl[((MI) * 16 + l4 * 4 + 3) * 36 + (NI) * 16 + l15] = C[3]; } while (0)
#define PRD(C, MI, NI) do { \
    C[0] += pl[((MI) * 16 + l4 * 4 + 0) * 36 + (NI) * 16 + l15]; \
    C[1] += pl[((MI) * 16 + l4 * 4 + 1) * 36 + (NI) * 16 + l15]; \
    C[2] += pl[((MI) * 16 + l4 * 4 + 2) * 36 + (NI) * 16 + l15]; \
    C[3] += pl[((MI) * 16 + l4 * 4 + 3) * 36 + (NI) * 16 + l15]; } while (0)

  if (kq) {
    float* pl = red + (size_t)(mh * 3 + kq - 1) * 1152;   // 32x36 plane
    PWR(c00, 0, 0); PWR(c01, 0, 1); PWR(c10, 1, 0); PWR(c11, 1, 1);
  }
  __syncthreads();
  if (kq == 0) {
#pragma unroll
    for (int p = 0; p < 3; ++p) {
      const float* pl = red + (size_t)(mh * 3 + p) * 1152;
      PRD(c00, 0, 0); PRD(c01, 0, 1); PRD(c10, 1, 0); PRD(c11, 1, 1);
    }
    float* ob = out + (size_t)(m0 + l4 * 4) * MOUT + n0 + l15;
#define STO(C, MI, NI) do { \
    ob[(size_t)((MI) * 16 + 0) * MOUT + (NI) * 16] = C[0]; \
    ob[(size_t)((MI) * 16 + 1) * MOUT + (NI) * 16] = C[1]; \
    ob[(size_t)((MI) * 16 + 2) * MOUT + (NI) * 16] = C[2]; \
    ob[(size_t)((MI) * 16 + 3) * MOUT + (NI) * 16] = C[3]; } while (0)
    STO(c00, 0, 0); STO(c01, 0, 1); STO(c10, 1, 0); STO(c11, 1, 1);
#undef STO
  }
#undef PWR
#undef PRD
}

extern "C" void kernel_launch(void* const* d_in, const int* in_sizes, int n_in,
                              void* d_out, int out_size, void* d_ws, size_t ws_size,
                              hipStream_t stream) {
  const float* inp = (const float*)d_in[0];
  const float* sw  = (const float*)d_in[1];
  const float* qs  = (const float*)d_in[2];
  const int*   qi  = (const int*)d_in[3];
  float* out = (float*)d_out;
  unsigned short* xa = (unsigned short*)d_ws;                  // 2 MB
  unsigned*       q2 = (unsigned*)((char*)d_ws + (4 << 20));   // 4 MB

  prep_kernel<<<512, 256, 0, stream>>>(inp, sw, qs, xa);
  repack_kernel<<<4096, 256, 0, stream>>>(qi, q2);
  gemm_kernel<<<512, 512, 0, stream>>>(xa, q2, out);
}